// Round 1
// baseline (14887.083 us; speedup 1.0000x reference)
//
#include <hip/hip_runtime.h>

// CNF fused RK4 integrator, bf16 MFMA for the H x H layer.
// Layout: one block = 128 samples (8 waves x 16), W2 staged once into LDS
// as bf16 MFMA-B fragments, all 36 aug evaluations fused.

typedef __attribute__((ext_vector_type(8))) short bf16x8;
typedef __attribute__((ext_vector_type(4))) float f32x4;

__device__ __forceinline__ unsigned short f2bf(float f) {
  unsigned u = __builtin_bit_cast(unsigned, f);
  u += 0x7FFFu + ((u >> 16) & 1u);   // round-to-nearest-even
  return (unsigned short)(u >> 16);
}

__device__ __forceinline__ float fast_tanh(float z) {
  float e = __expf(2.0f * z);
  return 1.0f - 2.0f * __builtin_amdgcn_rcpf(e + 1.0f);
}

__launch_bounds__(512, 2)
__global__ void cnf_rk4_kernel(const float* __restrict__ xg,
                               const float* __restrict__ W1,
                               const float* __restrict__ b1,
                               const float* __restrict__ W2,
                               const float* __restrict__ b2,
                               const float* __restrict__ W3,
                               const float* __restrict__ b3,
                               const int* __restrict__ nsp,
                               float* __restrict__ out,
                               int Btot) {
  // ---- LDS ----
  __shared__ __align__(16) unsigned short w2u[65536]; // 128 KB: W2 bf16, B-frag swizzled
  __shared__ float4 l1c[256];                         // (W1_0, W1_1, W1_2, b1) per k
  __shared__ float2 w3s[256];                         // W3 rows
  __shared__ float  b2s[256];
  __shared__ float  b3s[2];
  __shared__ float  cxs[128][2];                      // x at step start
  __shared__ float  sxs[128][2];                      // stage input x
  __shared__ float  ksum[128][2];                     // RK4 k-accumulator
  __shared__ float  lsum[128];                        // RK4 trace accumulator
  __shared__ float  lds_ld[128];                      // log_det

  const int tid  = threadIdx.x;
  const int lane = tid & 63;
  const int wv   = tid >> 6;       // wave 0..7
  const int ln15 = lane & 15;
  const int g    = lane >> 4;      // 0..3

  // ---- stage W2 -> LDS in B-fragment order ----
  // chunk c = kt*16 + n holds B[k= kt*32 + (l>>4)*8 + b][j= n*16 + (l&15)]
  for (int i = tid; i < 65536; i += 512) {
    int c = i >> 9, l = (i >> 3) & 63, bb = i & 7;
    int k = ((c >> 4) << 5) + ((l >> 4) << 3) + bb;
    int j = ((c & 15) << 4) + (l & 15);
    w2u[i] = f2bf(W2[k * 256 + j]);
  }
  for (int i = tid; i < 256; i += 512) {
    l1c[i] = make_float4(W1[i], W1[256 + i], W1[512 + i], b1[i]);
    w3s[i] = make_float2(W3[2 * i], W3[2 * i + 1]);
    b2s[i] = b2[i];
  }
  if (tid == 0) { b3s[0] = b3[0]; b3s[1] = b3[1]; }

  const int base = blockIdx.x * 128;
  for (int i = tid; i < 128; i += 512) {
    if (base + i < Btot) {
      float2 v = ((const float2*)xg)[base + i];
      cxs[i][0] = v.x; cxs[i][1] = v.y;
      sxs[i][0] = v.x; sxs[i][1] = v.y;
    } else {
      cxs[i][0] = 0.f; cxs[i][1] = 0.f; sxs[i][0] = 0.f; sxs[i][1] = 0.f;
    }
    lds_ld[i] = 0.0f;
  }
  __syncthreads();

  // n_steps: defensive decode (int expected; tolerate float encoding)
  int nst = nsp[0];
  if (nst < 1 || nst > 100000) {
    float fv = __builtin_bit_cast(float, nsp[0]);
    nst = (int)fv;
  }
  if (nst < 1) nst = 1;
  if (nst > 1000) nst = 1000;
  const int nsteps = nst - 1;
  const float hstep = (nsteps > 0) ? 1.0f / (float)nsteps : 0.0f;

  const bf16x8* w2v = (const bf16x8*)w2u;
  const int sA = wv * 16 + ln15;    // sample owned by this lane in A layout

  for (int step = 0; step < nsteps; ++step) {
    const float t0 = step * hstep;
    #pragma unroll 1
    for (int st = 0; st < 4; ++st) {
      const float tcur = t0 + ((st == 1 || st == 2) ? 0.5f * hstep
                                                    : (st == 3 ? hstep : 0.0f));
      // ---- layer 1 (VALU), directly in A-fragment layout ----
      const float x0 = sxs[sA][0];
      const float x1 = sxs[sA][1];
      bf16x8 hf[8], u0f[8], u1f[8];
      #pragma unroll
      for (int kt = 0; kt < 8; ++kt) {
        const int kbase = kt * 32 + g * 8;
        #pragma unroll
        for (int bb = 0; bb < 8; ++bb) {
          float4 q = l1c[kbase + bb];
          float z = fmaf(x0, q.x, fmaf(x1, q.y, fmaf(tcur, q.z, q.w)));
          float h = fast_tanh(z);
          float th = 1.0f - h * h;
          hf[kt][bb]  = (short)f2bf(h);
          u0f[kt][bb] = (short)f2bf(th * q.x);   // tangent e0: (1-h^2)*W1[0,k]
          u1f[kt][bb] = (short)f2bf(th * q.y);   // tangent e1: (1-h^2)*W1[1,k]
        }
      }
      // ---- layer 2 (MFMA) + layer-3 partials, N in quarters ----
      float po0[4] = {0,0,0,0}, po1[4] = {0,0,0,0}, ptr_[4] = {0,0,0,0};
      #pragma unroll 1
      for (int qn = 0; qn < 4; ++qn) {
        f32x4 aP[4], aU0[4], aU1[4];
        #pragma unroll
        for (int ni = 0; ni < 4; ++ni) {
          aP[ni] = (f32x4)0.0f; aU0[ni] = (f32x4)0.0f; aU1[ni] = (f32x4)0.0f;
        }
        #pragma unroll
        for (int kt = 0; kt < 8; ++kt) {
          #pragma unroll
          for (int ni = 0; ni < 4; ++ni) {
            const int c = kt * 16 + qn * 4 + ni;
            bf16x8 bf = w2v[c * 64 + lane];   // shared across 3 MFMAs
            aP[ni]  = __builtin_amdgcn_mfma_f32_16x16x32_bf16(hf[kt],  bf, aP[ni],  0, 0, 0);
            aU0[ni] = __builtin_amdgcn_mfma_f32_16x16x32_bf16(u0f[kt], bf, aU0[ni], 0, 0, 0);
            aU1[ni] = __builtin_amdgcn_mfma_f32_16x16x32_bf16(u1f[kt], bf, aU1[ni], 0, 0, 0);
          }
        }
        // epilogue: C layout row=(lane>>4)*4+reg (sample), col=lane&15 (j)
        #pragma unroll
        for (int ni = 0; ni < 4; ++ni) {
          const int j = (qn * 4 + ni) * 16 + ln15;
          const float bb2 = b2s[j];
          const float2 w3v = w3s[j];
          #pragma unroll
          for (int b = 0; b < 4; ++b) {
            float z2 = aP[ni][b] + bb2;
            float h2 = fast_tanh(z2);
            float th2 = 1.0f - h2 * h2;
            float d0 = th2 * aU0[ni][b];
            float d1 = th2 * aU1[ni][b];
            po0[b]  = fmaf(h2, w3v.x, po0[b]);
            po1[b]  = fmaf(h2, w3v.y, po1[b]);
            ptr_[b] = fmaf(d0, w3v.x, fmaf(d1, w3v.y, ptr_[b]));
          }
        }
      }
      // ---- reduce over the 16 j-lanes, then RK4 state update ----
      #pragma unroll
      for (int b = 0; b < 4; ++b) {
        float r0 = po0[b], r1 = po1[b], r2 = ptr_[b];
        #pragma unroll
        for (int off = 8; off > 0; off >>= 1) {
          r0 += __shfl_xor(r0, off, 64);
          r1 += __shfl_xor(r1, off, 64);
          r2 += __shfl_xor(r2, off, 64);
        }
        if (ln15 == 0) {             // leader lanes 0,16,32,48
          const int s = wv * 16 + g * 4 + b;
          const float dx0 = r0 + b3s[0];
          const float dx1 = r1 + b3s[1];
          const float trv = r2;
          float k0, k1v, kl;
          if (st == 0) { k0 = dx0; k1v = dx1; kl = trv; }
          else {
            const float w = (st == 3) ? 1.0f : 2.0f;
            k0 = ksum[s][0] + w * dx0; k1v = ksum[s][1] + w * dx1; kl = lsum[s] + w * trv;
          }
          ksum[s][0] = k0; ksum[s][1] = k1v; lsum[s] = kl;
          if (st < 3) {
            const float a = (st == 2) ? hstep : 0.5f * hstep;
            sxs[s][0] = cxs[s][0] + a * dx0;
            sxs[s][1] = cxs[s][1] + a * dx1;
          } else {
            const float c6 = hstep * (1.0f / 6.0f);
            const float nx0 = cxs[s][0] + c6 * k0;
            const float nx1 = cxs[s][1] + c6 * k1v;
            cxs[s][0] = nx0; cxs[s][1] = nx1;
            sxs[s][0] = nx0; sxs[s][1] = nx1;
            lds_ld[s] -= 0.01f * c6 * kl;   // -TRACE_SCALE * (h/6) * sum(tr)
          }
        }
      }
    }
  }
  __syncthreads();

  for (int i = tid; i < 128; i += 512) {
    const int gs = base + i;
    if (gs < Btot) {
      ((float2*)out)[gs] = make_float2(cxs[i][0], cxs[i][1]);
      out[2 * Btot + gs] = lds_ld[i];
    }
  }
}

extern "C" void kernel_launch(void* const* d_in, const int* in_sizes, int n_in,
                              void* d_out, int out_size, void* d_ws, size_t ws_size,
                              hipStream_t stream) {
  const float* x  = (const float*)d_in[0];
  const float* W1 = (const float*)d_in[1];
  const float* b1 = (const float*)d_in[2];
  const float* W2 = (const float*)d_in[3];
  const float* b2 = (const float*)d_in[4];
  const float* W3 = (const float*)d_in[5];
  const float* b3 = (const float*)d_in[6];
  const int* nsp  = (const int*)d_in[7];
  float* out = (float*)d_out;

  const int Btot = in_sizes[0] / 2;           // 262144
  const int nblocks = (Btot + 127) / 128;     // 2048

  cnf_rk4_kernel<<<dim3(nblocks), dim3(512), 0, stream>>>(
      x, W1, b1, W2, b2, W3, b3, nsp, out, Btot);
}

// Round 2
// 12277.270 us; speedup vs baseline: 1.2126x; 1.2126x over previous
//
#include <hip/hip_runtime.h>

// CNF fused RK4 integrator, bf16 MFMA, 2-chain formulation:
//   primal:  h1 x W2          (W2 bf16, staged in LDS, B-fragment layout)
//   trace:   (1-h1^2) x Btr   (Btr[k,j] = W2[k,j]*(W1[0,k]W3[j,0]+W1[1,k]W3[j,1]),
//                              bf16 in global d_ws, L1/L2-hot)
// One block = 128 samples (8 waves x 16). All 36 aug evals fused.

typedef __attribute__((ext_vector_type(8))) short bf16x8;
typedef __attribute__((ext_vector_type(8))) unsigned short u16x8;
typedef __attribute__((ext_vector_type(4))) float f32x4;

__device__ __forceinline__ unsigned short f2bf(float f) {
  unsigned u = __builtin_bit_cast(unsigned, f);
  u += 0x7FFFu + ((u >> 16) & 1u);   // RNE
  return (unsigned short)(u >> 16);
}

__device__ __forceinline__ float fast_tanh(float z) {
  float e = __expf(2.0f * z);
  return 1.0f - 2.0f * __builtin_amdgcn_rcpf(e + 1.0f);
}

// ---------- prep: swizzled bf16 W2 and Btr into d_ws ----------
// chunk c holds B[k = (c>>4)*32 + (l>>4)*8 + bb][j = (c&15)*16 + (l&15)]
// at index c*512 + l*8 + bb.
__global__ void cnf_prep(const float* __restrict__ W1,
                         const float* __restrict__ W2,
                         const float* __restrict__ W3,
                         unsigned short* __restrict__ w2s,
                         unsigned short* __restrict__ btrs) {
  int t = blockIdx.x * blockDim.x + threadIdx.x;  // 8192 threads, 8 elems each
  if (t >= 8192) return;
  int c = t >> 6, l = t & 63;
  int kbase = ((c >> 4) << 5) + ((l >> 4) << 3);
  int j = ((c & 15) << 4) + (l & 15);
  float w30 = W3[2 * j], w31 = W3[2 * j + 1];
  int o = t * 8;
  #pragma unroll
  for (int bb = 0; bb < 8; ++bb) {
    int k = kbase + bb;
    float w2 = W2[k * 256 + j];
    w2s[o + bb] = f2bf(w2);
    float coef = W1[k] * w30 + W1[256 + k] * w31;   // W1[0,k], W1[1,k]
    btrs[o + bb] = f2bf(w2 * coef);
  }
}

// ---------- main fused RK4 kernel (2-chain) ----------
__launch_bounds__(512, 2)
__global__ void cnf_rk4_v2(const float* __restrict__ xg,
                           const float* __restrict__ W1,
                           const float* __restrict__ b1,
                           const float* __restrict__ b2,
                           const float* __restrict__ W3,
                           const float* __restrict__ b3,
                           const unsigned short* __restrict__ w2s,
                           const unsigned short* __restrict__ btrs,
                           const int* __restrict__ nsp,
                           float* __restrict__ out,
                           int Btot) {
  __shared__ __align__(16) unsigned short w2u[65536]; // 128 KB
  __shared__ float4 l1c[256];                         // (W1_0, W1_1, W1_2, b1)
  __shared__ float4 eps[256];                         // (W3_0, W3_1, b2, 0)
  __shared__ float  b3s[2];
  __shared__ float  cxs[128][2];
  __shared__ float  sxs[128][2];
  __shared__ float  ksum[128][2];
  __shared__ float  lsum[128];
  __shared__ float  lds_ld[128];

  const int tid  = threadIdx.x;
  const int lane = tid & 63;
  const int wv   = tid >> 6;
  const int ln15 = lane & 15;
  const int g    = lane >> 4;

  // stage pre-swizzled W2 (vector copies from L2/L3)
  {
    u16x8* dst = (u16x8*)w2u;
    const u16x8* src = (const u16x8*)w2s;
    for (int i = tid; i < 8192; i += 512) dst[i] = src[i];
  }
  for (int i = tid; i < 256; i += 512) {
    l1c[i] = make_float4(W1[i], W1[256 + i], W1[512 + i], b1[i]);
    eps[i] = make_float4(W3[2 * i], W3[2 * i + 1], b2[i], 0.0f);
  }
  if (tid == 0) { b3s[0] = b3[0]; b3s[1] = b3[1]; }

  const int base = blockIdx.x * 128;
  for (int i = tid; i < 128; i += 512) {
    if (base + i < Btot) {
      float2 v = ((const float2*)xg)[base + i];
      cxs[i][0] = v.x; cxs[i][1] = v.y;
      sxs[i][0] = v.x; sxs[i][1] = v.y;
    } else {
      cxs[i][0] = 0.f; cxs[i][1] = 0.f; sxs[i][0] = 0.f; sxs[i][1] = 0.f;
    }
    lds_ld[i] = 0.0f;
  }
  __syncthreads();

  int nst = nsp[0];
  if (nst < 1 || nst > 100000) {
    float fv = __builtin_bit_cast(float, nsp[0]);
    nst = (int)fv;
  }
  if (nst < 1) nst = 1;
  if (nst > 1000) nst = 1000;
  const int nsteps = nst - 1;
  const float hstep = (nsteps > 0) ? 1.0f / (float)nsteps : 0.0f;

  const bf16x8* w2v  = (const bf16x8*)w2u;
  const bf16x8* btrv = (const bf16x8*)btrs;
  const int sA = wv * 16 + ln15;

  for (int step = 0; step < nsteps; ++step) {
    const float t0 = step * hstep;
    #pragma unroll 1
    for (int st = 0; st < 4; ++st) {
      const float tcur = t0 + ((st == 1 || st == 2) ? 0.5f * hstep
                                                    : (st == 3 ? hstep : 0.0f));
      // ---- layer 1 (VALU) in A-fragment layout ----
      const float x0 = sxs[sA][0];
      const float x1 = sxs[sA][1];
      bf16x8 hf[8], tf[8];
      #pragma unroll
      for (int kt = 0; kt < 8; ++kt) {
        const int kbase = kt * 32 + g * 8;
        #pragma unroll
        for (int bb = 0; bb < 8; ++bb) {
          float4 q = l1c[kbase + bb];
          float z = fmaf(x0, q.x, fmaf(x1, q.y, fmaf(tcur, q.z, q.w)));
          float h = fast_tanh(z);
          hf[kt][bb] = (short)f2bf(h);
          tf[kt][bb] = (short)f2bf(1.0f - h * h);
        }
      }
      // ---- layer 2: 2 MFMA chains, N in quarters ----
      float po0[4] = {0,0,0,0}, po1[4] = {0,0,0,0}, ptr_[4] = {0,0,0,0};
      #pragma unroll 1
      for (int qn = 0; qn < 4; ++qn) {
        f32x4 aP[4], aT[4];
        #pragma unroll
        for (int ni = 0; ni < 4; ++ni) { aP[ni] = (f32x4)0.0f; aT[ni] = (f32x4)0.0f; }
        #pragma unroll
        for (int kt = 0; kt < 8; ++kt) {
          #pragma unroll
          for (int ni = 0; ni < 4; ++ni) {
            const int c = kt * 16 + qn * 4 + ni;
            bf16x8 bw = w2v[c * 64 + lane];        // LDS
            bf16x8 bt = btrv[c * 64 + lane];       // global (L1/L2-hot)
            aP[ni] = __builtin_amdgcn_mfma_f32_16x16x32_bf16(hf[kt], bw, aP[ni], 0, 0, 0);
            aT[ni] = __builtin_amdgcn_mfma_f32_16x16x32_bf16(tf[kt], bt, aT[ni], 0, 0, 0);
          }
        }
        // epilogue: C layout col=lane&15 (j), row=(lane>>4)*4+b (sample)
        #pragma unroll
        for (int ni = 0; ni < 4; ++ni) {
          const int j = (qn * 4 + ni) * 16 + ln15;
          const float4 e = eps[j];                 // w30, w31, b2
          #pragma unroll
          for (int b = 0; b < 4; ++b) {
            float z2 = aP[ni][b] + e.z;
            float h2 = fast_tanh(z2);
            float th2 = 1.0f - h2 * h2;
            po0[b]  = fmaf(h2, e.x, po0[b]);
            po1[b]  = fmaf(h2, e.y, po1[b]);
            ptr_[b] = fmaf(th2, aT[ni][b], ptr_[b]);
          }
        }
      }
      // ---- reduce over 16 j-lanes, RK4 state update ----
      #pragma unroll
      for (int b = 0; b < 4; ++b) {
        float r0 = po0[b], r1 = po1[b], r2 = ptr_[b];
        #pragma unroll
        for (int off = 8; off > 0; off >>= 1) {
          r0 += __shfl_xor(r0, off, 64);
          r1 += __shfl_xor(r1, off, 64);
          r2 += __shfl_xor(r2, off, 64);
        }
        if (ln15 == 0) {
          const int s = wv * 16 + g * 4 + b;
          const float dx0 = r0 + b3s[0];
          const float dx1 = r1 + b3s[1];
          const float trv = r2;
          float k0, k1v, kl;
          if (st == 0) { k0 = dx0; k1v = dx1; kl = trv; }
          else {
            const float w = (st == 3) ? 1.0f : 2.0f;
            k0 = ksum[s][0] + w * dx0; k1v = ksum[s][1] + w * dx1; kl = lsum[s] + w * trv;
          }
          ksum[s][0] = k0; ksum[s][1] = k1v; lsum[s] = kl;
          if (st < 3) {
            const float a = (st == 2) ? hstep : 0.5f * hstep;
            sxs[s][0] = cxs[s][0] + a * dx0;
            sxs[s][1] = cxs[s][1] + a * dx1;
          } else {
            const float c6 = hstep * (1.0f / 6.0f);
            const float nx0 = cxs[s][0] + c6 * k0;
            const float nx1 = cxs[s][1] + c6 * k1v;
            cxs[s][0] = nx0; cxs[s][1] = nx1;
            sxs[s][0] = nx0; sxs[s][1] = nx1;
            lds_ld[s] -= 0.01f * c6 * kl;
          }
        }
      }
    }
  }
  __syncthreads();

  for (int i = tid; i < 128; i += 512) {
    const int gs = base + i;
    if (gs < Btot) {
      ((float2*)out)[gs] = make_float2(cxs[i][0], cxs[i][1]);
      out[2 * Btot + gs] = lds_ld[i];
    }
  }
}

// ---------- fallback (proven round-1 kernel, used only if ws too small) ----------
__launch_bounds__(512, 2)
__global__ void cnf_rk4_fb(const float* __restrict__ xg,
                           const float* __restrict__ W1,
                           const float* __restrict__ b1,
                           const float* __restrict__ W2,
                           const float* __restrict__ b2,
                           const float* __restrict__ W3,
                           const float* __restrict__ b3,
                           const int* __restrict__ nsp,
                           float* __restrict__ out,
                           int Btot) {
  __shared__ __align__(16) unsigned short w2u[65536];
  __shared__ float4 l1c[256];
  __shared__ float2 w3s[256];
  __shared__ float  b2s[256];
  __shared__ float  b3s[2];
  __shared__ float  cxs[128][2];
  __shared__ float  sxs[128][2];
  __shared__ float  ksum[128][2];
  __shared__ float  lsum[128];
  __shared__ float  lds_ld[128];

  const int tid  = threadIdx.x;
  const int lane = tid & 63;
  const int wv   = tid >> 6;
  const int ln15 = lane & 15;
  const int g    = lane >> 4;

  for (int i = tid; i < 65536; i += 512) {
    int c = i >> 9, l = (i >> 3) & 63, bb = i & 7;
    int k = ((c >> 4) << 5) + ((l >> 4) << 3) + bb;
    int j = ((c & 15) << 4) + (l & 15);
    w2u[i] = f2bf(W2[k * 256 + j]);
  }
  for (int i = tid; i < 256; i += 512) {
    l1c[i] = make_float4(W1[i], W1[256 + i], W1[512 + i], b1[i]);
    w3s[i] = make_float2(W3[2 * i], W3[2 * i + 1]);
    b2s[i] = b2[i];
  }
  if (tid == 0) { b3s[0] = b3[0]; b3s[1] = b3[1]; }

  const int base = blockIdx.x * 128;
  for (int i = tid; i < 128; i += 512) {
    if (base + i < Btot) {
      float2 v = ((const float2*)xg)[base + i];
      cxs[i][0] = v.x; cxs[i][1] = v.y;
      sxs[i][0] = v.x; sxs[i][1] = v.y;
    } else {
      cxs[i][0] = 0.f; cxs[i][1] = 0.f; sxs[i][0] = 0.f; sxs[i][1] = 0.f;
    }
    lds_ld[i] = 0.0f;
  }
  __syncthreads();

  int nst = nsp[0];
  if (nst < 1 || nst > 100000) { float fv = __builtin_bit_cast(float, nsp[0]); nst = (int)fv; }
  if (nst < 1) nst = 1;
  if (nst > 1000) nst = 1000;
  const int nsteps = nst - 1;
  const float hstep = (nsteps > 0) ? 1.0f / (float)nsteps : 0.0f;

  const bf16x8* w2v = (const bf16x8*)w2u;
  const int sA = wv * 16 + ln15;

  for (int step = 0; step < nsteps; ++step) {
    const float t0 = step * hstep;
    #pragma unroll 1
    for (int st = 0; st < 4; ++st) {
      const float tcur = t0 + ((st == 1 || st == 2) ? 0.5f * hstep
                                                    : (st == 3 ? hstep : 0.0f));
      const float x0 = sxs[sA][0];
      const float x1 = sxs[sA][1];
      bf16x8 hf[8], u0f[8], u1f[8];
      #pragma unroll
      for (int kt = 0; kt < 8; ++kt) {
        const int kbase = kt * 32 + g * 8;
        #pragma unroll
        for (int bb = 0; bb < 8; ++bb) {
          float4 q = l1c[kbase + bb];
          float z = fmaf(x0, q.x, fmaf(x1, q.y, fmaf(tcur, q.z, q.w)));
          float h = fast_tanh(z);
          float th = 1.0f - h * h;
          hf[kt][bb]  = (short)f2bf(h);
          u0f[kt][bb] = (short)f2bf(th * q.x);
          u1f[kt][bb] = (short)f2bf(th * q.y);
        }
      }
      float po0[4] = {0,0,0,0}, po1[4] = {0,0,0,0}, ptr_[4] = {0,0,0,0};
      #pragma unroll 1
      for (int qn = 0; qn < 4; ++qn) {
        f32x4 aP[4], aU0[4], aU1[4];
        #pragma unroll
        for (int ni = 0; ni < 4; ++ni) {
          aP[ni] = (f32x4)0.0f; aU0[ni] = (f32x4)0.0f; aU1[ni] = (f32x4)0.0f;
        }
        #pragma unroll
        for (int kt = 0; kt < 8; ++kt) {
          #pragma unroll
          for (int ni = 0; ni < 4; ++ni) {
            const int c = kt * 16 + qn * 4 + ni;
            bf16x8 bf = w2v[c * 64 + lane];
            aP[ni]  = __builtin_amdgcn_mfma_f32_16x16x32_bf16(hf[kt],  bf, aP[ni],  0, 0, 0);
            aU0[ni] = __builtin_amdgcn_mfma_f32_16x16x32_bf16(u0f[kt], bf, aU0[ni], 0, 0, 0);
            aU1[ni] = __builtin_amdgcn_mfma_f32_16x16x32_bf16(u1f[kt], bf, aU1[ni], 0, 0, 0);
          }
        }
        #pragma unroll
        for (int ni = 0; ni < 4; ++ni) {
          const int j = (qn * 4 + ni) * 16 + ln15;
          const float bb2 = b2s[j];
          const float2 w3v = w3s[j];
          #pragma unroll
          for (int b = 0; b < 4; ++b) {
            float z2 = aP[ni][b] + bb2;
            float h2 = fast_tanh(z2);
            float th2 = 1.0f - h2 * h2;
            float d0 = th2 * aU0[ni][b];
            float d1 = th2 * aU1[ni][b];
            po0[b]  = fmaf(h2, w3v.x, po0[b]);
            po1[b]  = fmaf(h2, w3v.y, po1[b]);
            ptr_[b] = fmaf(d0, w3v.x, fmaf(d1, w3v.y, ptr_[b]));
          }
        }
      }
      #pragma unroll
      for (int b = 0; b < 4; ++b) {
        float r0 = po0[b], r1 = po1[b], r2 = ptr_[b];
        #pragma unroll
        for (int off = 8; off > 0; off >>= 1) {
          r0 += __shfl_xor(r0, off, 64);
          r1 += __shfl_xor(r1, off, 64);
          r2 += __shfl_xor(r2, off, 64);
        }
        if (ln15 == 0) {
          const int s = wv * 16 + g * 4 + b;
          const float dx0 = r0 + b3s[0];
          const float dx1 = r1 + b3s[1];
          const float trv = r2;
          float k0, k1v, kl;
          if (st == 0) { k0 = dx0; k1v = dx1; kl = trv; }
          else {
            const float w = (st == 3) ? 1.0f : 2.0f;
            k0 = ksum[s][0] + w * dx0; k1v = ksum[s][1] + w * dx1; kl = lsum[s] + w * trv;
          }
          ksum[s][0] = k0; ksum[s][1] = k1v; lsum[s] = kl;
          if (st < 3) {
            const float a = (st == 2) ? hstep : 0.5f * hstep;
            sxs[s][0] = cxs[s][0] + a * dx0;
            sxs[s][1] = cxs[s][1] + a * dx1;
          } else {
            const float c6 = hstep * (1.0f / 6.0f);
            const float nx0 = cxs[s][0] + c6 * k0;
            const float nx1 = cxs[s][1] + c6 * k1v;
            cxs[s][0] = nx0; cxs[s][1] = nx1;
            sxs[s][0] = nx0; sxs[s][1] = nx1;
            lds_ld[s] -= 0.01f * c6 * kl;
          }
        }
      }
    }
  }
  __syncthreads();

  for (int i = tid; i < 128; i += 512) {
    const int gs = base + i;
    if (gs < Btot) {
      ((float2*)out)[gs] = make_float2(cxs[i][0], cxs[i][1]);
      out[2 * Btot + gs] = lds_ld[i];
    }
  }
}

extern "C" void kernel_launch(void* const* d_in, const int* in_sizes, int n_in,
                              void* d_out, int out_size, void* d_ws, size_t ws_size,
                              hipStream_t stream) {
  const float* x  = (const float*)d_in[0];
  const float* W1 = (const float*)d_in[1];
  const float* b1 = (const float*)d_in[2];
  const float* W2 = (const float*)d_in[3];
  const float* b2 = (const float*)d_in[4];
  const float* W3 = (const float*)d_in[5];
  const float* b3 = (const float*)d_in[6];
  const int* nsp  = (const int*)d_in[7];
  float* out = (float*)d_out;

  const int Btot = in_sizes[0] / 2;
  const int nblocks = (Btot + 127) / 128;

  if (ws_size >= 2u * 65536u * sizeof(unsigned short)) {
    unsigned short* w2s  = (unsigned short*)d_ws;
    unsigned short* btrs = w2s + 65536;
    cnf_prep<<<dim3(32), dim3(256), 0, stream>>>(W1, W2, W3, w2s, btrs);
    cnf_rk4_v2<<<dim3(nblocks), dim3(512), 0, stream>>>(
        x, W1, b1, b2, W3, b3, w2s, btrs, nsp, out, Btot);
  } else {
    cnf_rk4_fb<<<dim3(nblocks), dim3(512), 0, stream>>>(
        x, W1, b1, W2, b2, W3, b3, nsp, out, Btot);
  }
}